// Round 1
// baseline (232.633 us; speedup 1.0000x reference)
//
#include <hip/hip_runtime.h>
#include <hip/hip_bf16.h>
#include <hip/hip_cooperative_groups.h>

// Problem constants (from reference): N=100000, F=128, E=640000, OUT=16
#define F_DIM 128
#define OUT_DIM 16

namespace cg = cooperative_groups;

typedef _Float16 half8 __attribute__((ext_vector_type(8)));
typedef float floatx4 __attribute__((ext_vector_type(4)));
typedef unsigned short us8 __attribute__((ext_vector_type(8)));

__device__ __forceinline__ unsigned bf16_bits_rne(float f) {
    unsigned u = __builtin_bit_cast(unsigned, f);
    unsigned rounding = 0x7FFFu + ((u >> 16) & 1u);
    return (u + rounding) >> 16;          // RNE; NaN not possible here
}

// ---------------------------------------------------------------------------
// FUSED cooperative kernel: wprep (LDS) -> proj (grid-stride) -> grid.sync()
// -> gather (grid-stride). Math byte-identical to the 3-kernel version.
__global__ __launch_bounds__(256) void fused_kernel(
    const float* __restrict__ h, const int* __restrict__ src,
    const int* __restrict__ dst, const float* __restrict__ W,
    const float* __restrict__ b, float* __restrict__ out,
    unsigned int* __restrict__ Pu16, unsigned int* __restrict__ Pv16,
    int N, int E)
{
    // ---- Phase 0: W -> fp16 hi/lo fragment tables, per-block in LDS -------
    // Same index math as the old wprep_kernel; 8 KB per table, read L1/L2-hot.
    __shared__ __align__(16) _Float16 sBhi[4096];
    __shared__ __align__(16) _Float16 sBlo[4096];
    for (int i = threadIdx.x; i < 4096; i += 256) {
        int j    = i & 7;
        int ln   = (i >> 3) & 63;
        int t    = (i >> 9) & 1;
        int s    = (i >> 10) & 3;
        int n2 = ln & 15;
        int q2 = ln >> 4;
        int k = s * 32 + q2 * 8 + j;
        float w = W[n2 * 256 + t * 128 + k];
        _Float16 hi = (_Float16)w;
        sBhi[i] = hi;
        sBlo[i] = (_Float16)(w - (float)hi);
    }
    __syncthreads();

    const int lane = threadIdx.x & 63;
    const int wave = threadIdx.x >> 6;
    const int n = lane & 15;            // node within tile
    const int q = lane >> 4;            // quad: o-group and k-group selector
    const floatx4 bv = *(const floatx4*)(b + 4 * q);   // b[4q+reg]

    // ---- Phase 1: Pu16[node][o] = bf16(h[node].Wu + b); Pv16 likewise -----
    // TRANSPOSED MFMA identical to proj_mfma_kernel, grid-strided over tiles.
    const int nTiles = (N + 15) >> 4;                 // 6250 (N % 16 == 0)
    const int waveId = blockIdx.x * 4 + wave;
    const int nWaves = gridDim.x * 4;
    for (int tile = waveId; tile < nTiles; tile += nWaves) {
        const int row_base = tile * 16;
        int arow = row_base + n;
        if (arow >= N) arow = N - 1;                  // safety; N%16==0 so unused
        const float* hrow = h + (size_t)arow * F_DIM + q * 8;

        floatx4 c0 = {0.f, 0.f, 0.f, 0.f};           // u half: D[o][node]
        floatx4 c1 = {0.f, 0.f, 0.f, 0.f};           // v half

        #pragma unroll
        for (int s = 0; s < 4; ++s) {
            float av[8];
            *(floatx4*)(av)     = *(const floatx4*)(hrow + s * 32);
            *(floatx4*)(av + 4) = *(const floatx4*)(hrow + s * 32 + 4);
            half8 ah, al;
            #pragma unroll
            for (int j = 0; j < 8; ++j) {
                _Float16 hi = (_Float16)av[j];
                ah[j] = hi;
                al[j] = (_Float16)(av[j] - (float)hi);
            }
            const int base0 = (s * 2 + 0) * 512 + lane * 8;
            const int base1 = (s * 2 + 1) * 512 + lane * 8;
            half8 wh0 = *(const half8*)(sBhi + base0);
            half8 wl0 = *(const half8*)(sBlo + base0);
            half8 wh1 = *(const half8*)(sBhi + base1);
            half8 wl1 = *(const half8*)(sBlo + base1);

            c0 = __builtin_amdgcn_mfma_f32_16x16x32_f16(wh0, ah, c0, 0, 0, 0);
            c0 = __builtin_amdgcn_mfma_f32_16x16x32_f16(wl0, ah, c0, 0, 0, 0);
            c0 = __builtin_amdgcn_mfma_f32_16x16x32_f16(wh0, al, c0, 0, 0, 0);
            c1 = __builtin_amdgcn_mfma_f32_16x16x32_f16(wh1, ah, c1, 0, 0, 0);
            c1 = __builtin_amdgcn_mfma_f32_16x16x32_f16(wl1, ah, c1, 0, 0, 0);
            c1 = __builtin_amdgcn_mfma_f32_16x16x32_f16(wh1, al, c1, 0, 0, 0);
        }

        const int node = row_base + n;
        if (node < N) {
            unsigned u0 = bf16_bits_rne(c0[0] + bv[0]) | (bf16_bits_rne(c0[1] + bv[1]) << 16);
            unsigned u1 = bf16_bits_rne(c0[2] + bv[2]) | (bf16_bits_rne(c0[3] + bv[3]) << 16);
            unsigned v0 = bf16_bits_rne(c1[0]) | (bf16_bits_rne(c1[1]) << 16);
            unsigned v1 = bf16_bits_rne(c1[2]) | (bf16_bits_rne(c1[3]) << 16);
            const size_t base = (size_t)node * 8 + 2 * q;
            Pu16[base]     = u0;
            Pu16[base + 1] = u1;
            Pv16[base]     = v0;
            Pv16[base + 1] = v1;
        }
    }

    // Tables must be visible across XCDs before any block gathers.
    __threadfence();
    cg::this_grid().sync();

    // ---- Phase 2: out[e][o] = Pu[src[e]][o] + Pv[dst[e]][o] ---------------
    // Byte-identical task decomposition to the proven gather (2 lanes/edge,
    // 16B bf16 loads per table, <<16 converts, 32B contiguous NT stores).
    const unsigned short* Pu = (const unsigned short*)Pu16;
    const unsigned short* Pv = (const unsigned short*)Pv16;
    const int tid0   = blockIdx.x * 256 + threadIdx.x;
    const int stride = gridDim.x * 256;
    const int total  = 2 * E;
    for (int t = tid0; t < total; t += stride) {
        const int e  = t >> 1;
        const int qq = t & 1;
        const int si = src[e];
        const int di = dst[e];
        const us8 pu = *(const us8*)(Pu + (size_t)si * 16 + qq * 8);
        const us8 pv = *(const us8*)(Pv + (size_t)di * 16 + qq * 8);
        floatx4 r0, r1;
        #pragma unroll
        for (int j = 0; j < 4; ++j) {
            r0[j] = __uint_as_float((unsigned)pu[j] << 16)
                  + __uint_as_float((unsigned)pv[j] << 16);
            r1[j] = __uint_as_float((unsigned)pu[j + 4] << 16)
                  + __uint_as_float((unsigned)pv[j + 4] << 16);
        }
        floatx4* o = (floatx4*)out + (size_t)t * 2;
        __builtin_nontemporal_store(r0, o);
        __builtin_nontemporal_store(r1, o + 1);
    }
}

// ---------------------------------------------------------------------------
// Fallback path: the previous verified 3-kernel pipeline (unchanged), used if
// cooperative launch is unavailable (e.g. rejected under graph capture).
__global__ __launch_bounds__(256) void wprep_kernel(
    const float* __restrict__ W, _Float16* __restrict__ Bhi,
    _Float16* __restrict__ Blo)
{
    int tid = blockIdx.x * 256 + threadIdx.x;     // 0..4095
    if (tid >= 4096) return;
    int j    = tid & 7;
    int lane = (tid >> 3) & 63;
    int t    = (tid >> 9) & 1;
    int s    = (tid >> 10) & 3;
    int n = lane & 15;
    int q = lane >> 4;
    int k = s * 32 + q * 8 + j;
    float w = W[n * 256 + t * 128 + k];
    _Float16 hi = (_Float16)w;
    _Float16 lo = (_Float16)(w - (float)hi);
    Bhi[tid] = hi;
    Blo[tid] = lo;
}

__global__ __launch_bounds__(256) void proj_mfma_kernel(
    const float* __restrict__ h, const _Float16* __restrict__ Bhi,
    const _Float16* __restrict__ Blo, const float* __restrict__ b,
    unsigned int* __restrict__ Pu16, unsigned int* __restrict__ Pv16, int N)
{
    const int lane = threadIdx.x & 63;
    const int wave = threadIdx.x >> 6;
    const int n = lane & 15;
    const int q = lane >> 4;
    const int row_base = blockIdx.x * 64 + wave * 16;
    if (row_base >= N) return;

    int arow = row_base + n;
    if (arow >= N) arow = N - 1;
    const float* hrow = h + (size_t)arow * F_DIM + q * 8;

    floatx4 c0 = {0.f, 0.f, 0.f, 0.f};
    floatx4 c1 = {0.f, 0.f, 0.f, 0.f};

    #pragma unroll
    for (int s = 0; s < 4; ++s) {
        float av[8];
        *(floatx4*)(av)     = *(const floatx4*)(hrow + s * 32);
        *(floatx4*)(av + 4) = *(const floatx4*)(hrow + s * 32 + 4);
        half8 ah, al;
        #pragma unroll
        for (int j = 0; j < 8; ++j) {
            _Float16 hi = (_Float16)av[j];
            ah[j] = hi;
            al[j] = (_Float16)(av[j] - (float)hi);
        }
        const int base0 = (s * 2 + 0) * 512 + lane * 8;
        const int base1 = (s * 2 + 1) * 512 + lane * 8;
        half8 wh0 = *(const half8*)(Bhi + base0);
        half8 wl0 = *(const half8*)(Blo + base0);
        half8 wh1 = *(const half8*)(Bhi + base1);
        half8 wl1 = *(const half8*)(Blo + base1);

        c0 = __builtin_amdgcn_mfma_f32_16x16x32_f16(wh0, ah, c0, 0, 0, 0);
        c0 = __builtin_amdgcn_mfma_f32_16x16x32_f16(wl0, ah, c0, 0, 0, 0);
        c0 = __builtin_amdgcn_mfma_f32_16x16x32_f16(wh0, al, c0, 0, 0, 0);
        c1 = __builtin_amdgcn_mfma_f32_16x16x32_f16(wh1, ah, c1, 0, 0, 0);
        c1 = __builtin_amdgcn_mfma_f32_16x16x32_f16(wl1, ah, c1, 0, 0, 0);
        c1 = __builtin_amdgcn_mfma_f32_16x16x32_f16(wh1, al, c1, 0, 0, 0);
    }

    const int node = row_base + n;
    if (node < N) {
        const floatx4 bv = *(const floatx4*)(b + 4 * q);
        unsigned u0 = bf16_bits_rne(c0[0] + bv[0]) | (bf16_bits_rne(c0[1] + bv[1]) << 16);
        unsigned u1 = bf16_bits_rne(c0[2] + bv[2]) | (bf16_bits_rne(c0[3] + bv[3]) << 16);
        unsigned v0 = bf16_bits_rne(c1[0]) | (bf16_bits_rne(c1[1]) << 16);
        unsigned v1 = bf16_bits_rne(c1[2]) | (bf16_bits_rne(c1[3]) << 16);
        const size_t base = (size_t)node * 8 + 2 * q;
        Pu16[base]     = u0;
        Pu16[base + 1] = u1;
        Pv16[base]     = v0;
        Pv16[base + 1] = v1;
    }
}

__global__ __launch_bounds__(256) void gather_kernel(
    const unsigned short* __restrict__ Pu, const unsigned short* __restrict__ Pv,
    const int* __restrict__ src, const int* __restrict__ dst,
    float* __restrict__ out, int E)
{
    const int tid = blockIdx.x * blockDim.x + threadIdx.x;
    const int e = tid >> 1;
    const int q = tid & 1;
    if (e >= E) return;
    const int s = src[e];
    const int d = dst[e];
    const us8 pu = *(const us8*)(Pu + (size_t)s * 16 + q * 8);
    const us8 pv = *(const us8*)(Pv + (size_t)d * 16 + q * 8);
    floatx4 r0, r1;
    #pragma unroll
    for (int j = 0; j < 4; ++j) {
        r0[j] = __uint_as_float((unsigned)pu[j] << 16)
              + __uint_as_float((unsigned)pv[j] << 16);
        r1[j] = __uint_as_float((unsigned)pu[j + 4] << 16)
              + __uint_as_float((unsigned)pv[j + 4] << 16);
    }
    floatx4* o = (floatx4*)out + (size_t)tid * 2;
    __builtin_nontemporal_store(r0, o);
    __builtin_nontemporal_store(r1, o + 1);
}

__global__ __launch_bounds__(256) void direct_kernel(
    const float* __restrict__ h, const int* __restrict__ src,
    const int* __restrict__ dst, const float* __restrict__ W,
    const float* __restrict__ b, float* __restrict__ out, int E)
{
    const int tid = blockIdx.x * blockDim.x + threadIdx.x;
    if (tid >= E * OUT_DIM) return;
    const int e = tid >> 4;
    const int o = tid & 15;
    const float* hu = h + (size_t)src[e] * F_DIM;
    const float* hv = h + (size_t)dst[e] * F_DIM;
    const float* wu = W + (size_t)o * 256;
    const float* wv = wu + 128;
    float acc = b[o];
    for (int k = 0; k < 128; ++k) acc = fmaf(hu[k], wu[k], acc);
    for (int k = 0; k < 128; ++k) acc = fmaf(hv[k], wv[k], acc);
    out[tid] = acc;
}

extern "C" void kernel_launch(void* const* d_in, const int* in_sizes, int n_in,
                              void* d_out, int out_size, void* d_ws, size_t ws_size,
                              hipStream_t stream) {
    const float* h   = (const float*)d_in[0];
    const int*   src = (const int*)d_in[1];
    const int*   dst = (const int*)d_in[2];
    const float* W   = (const float*)d_in[3];
    const float* b   = (const float*)d_in[4];
    float* out = (float*)d_out;

    int N = in_sizes[0] / F_DIM;     // 100000
    int E = in_sizes[1];             // 640000

    const size_t p16_bytes = (size_t)N * 8 * sizeof(unsigned);    // 3.2 MB
    const size_t p16_al    = (p16_bytes + 255) & ~(size_t)255;
    const size_t bf_bytes  = 4096 * sizeof(_Float16);             // 8 KB each

    if (ws_size < 2 * p16_al + 2 * bf_bytes) {
        const int total  = E * OUT_DIM;
        const int blocks = (total + 255) / 256;
        direct_kernel<<<blocks, 256, 0, stream>>>(h, src, dst, W, b, out, E);
        return;
    }

    unsigned int* Pu16 = (unsigned int*)d_ws;
    unsigned int* Pv16 = (unsigned int*)((char*)d_ws + p16_al);
    _Float16*     Bhi  = (_Float16*)((char*)d_ws + 2 * p16_al);
    _Float16*     Blo  = Bhi + 4096;

    // Co-residency grid sizing for the cooperative kernel (cached).
    static int s_grid = -2;                    // -2 uninit, -1 unavailable
    if (s_grid == -2) {
        int nBlk = 0;
        if (hipOccupancyMaxActiveBlocksPerMultiprocessor(
                &nBlk, fused_kernel, 256, 0) != hipSuccess || nBlk <= 0) {
            s_grid = -1;
        } else {
            int dev = 0, nCU = 0;
            hipGetDevice(&dev);
            if (hipDeviceGetAttribute(&nCU, hipDeviceAttributeMultiprocessorCount,
                                      dev) != hipSuccess || nCU <= 0)
                nCU = 256;
            long g = (long)nBlk * (long)nCU;
            if (g > 2048) g = 2048;            // cap: plenty of waves already
            s_grid = (int)g;
        }
    }

    if (s_grid > 0) {
        void* args[] = { (void*)&h, (void*)&src, (void*)&dst, (void*)&W,
                         (void*)&b, (void*)&out, (void*)&Pu16, (void*)&Pv16,
                         (void*)&N, (void*)&E };
        hipError_t err = hipLaunchCooperativeKernel(
            (const void*)fused_kernel, dim3(s_grid), dim3(256), args, 0, stream);
        if (err == hipSuccess) return;
        s_grid = -1;                           // don't retry next time
    }

    // Fallback: previous verified 3-kernel pipeline.
    wprep_kernel<<<16, 256, 0, stream>>>(W, Bhi, Blo);
    const int blocks1 = (N + 63) / 64;
    proj_mfma_kernel<<<blocks1, 256, 0, stream>>>(h, Bhi, Blo, b, Pu16, Pv16, N);
    const int total2  = E * 2;
    const int blocks2 = (total2 + 255) / 256;
    gather_kernel<<<blocks2, 256, 0, stream>>>(
        (const unsigned short*)Pu16, (const unsigned short*)Pv16,
        src, dst, out, E);
}

// Round 3
// 154.731 us; speedup vs baseline: 1.5035x; 1.5035x over previous
//
#include <hip/hip_runtime.h>
#include <hip/hip_bf16.h>

// Problem constants (from reference): N=100000, F=128, E=640000, OUT=16
#define F_DIM 128
#define OUT_DIM 16

typedef _Float16 half8 __attribute__((ext_vector_type(8)));
typedef float floatx4 __attribute__((ext_vector_type(4)));
typedef unsigned short us8 __attribute__((ext_vector_type(8)));
typedef int intx2 __attribute__((ext_vector_type(2)));

// ---------------------------------------------------------------------------
// Kernel 0: build fp16 hi/lo weight fragments (k = quad*8+j, lane&15 = o).
// 8 KB per term, read L1-hot as wave-uniform broadcasts in proj.
__global__ __launch_bounds__(256) void wprep_kernel(
    const float* __restrict__ W, _Float16* __restrict__ Bhi,
    _Float16* __restrict__ Blo)
{
    int tid = blockIdx.x * 256 + threadIdx.x;     // 0..4095
    if (tid >= 4096) return;
    int j    = tid & 7;
    int lane = (tid >> 3) & 63;
    int t    = (tid >> 9) & 1;
    int s    = (tid >> 10) & 3;
    int n = lane & 15;
    int q = lane >> 4;
    int k = s * 32 + q * 8 + j;
    float w = W[n * 256 + t * 128 + k];
    _Float16 hi = (_Float16)w;
    _Float16 lo = (_Float16)(w - (float)hi);
    Bhi[tid] = hi;
    Blo[tid] = lo;
}

__device__ __forceinline__ unsigned bf16_bits_rne(float f) {
    unsigned u = __builtin_bit_cast(unsigned, f);
    unsigned rounding = 0x7FFFu + ((u >> 16) & 1u);
    return (u + rounding) >> 16;          // RNE; NaN not possible here
}

// ---------------------------------------------------------------------------
// Kernel 1: Pu16[node][o] = bf16(h[node].Wu + b) ; Pv16 likewise (no bias).
// TRANSPOSED MFMA: D[m=o][n=node] = sum_k W'[o][k] * h[node][k]
// Byte-identical to the verified 125.9 µs baseline.
__global__ __launch_bounds__(256) void proj_mfma_kernel(
    const float* __restrict__ h, const _Float16* __restrict__ Bhi,
    const _Float16* __restrict__ Blo, const float* __restrict__ b,
    unsigned int* __restrict__ Pu16, unsigned int* __restrict__ Pv16, int N)
{
    const int lane = threadIdx.x & 63;
    const int wave = threadIdx.x >> 6;
    const int n = lane & 15;            // node within tile
    const int q = lane >> 4;            // quad: o-group and k-group selector
    const int row_base = blockIdx.x * 64 + wave * 16;
    if (row_base >= N) return;          // whole wave exits; no barriers below

    int arow = row_base + n;            // h row this lane feeds (B operand)
    if (arow >= N) arow = N - 1;        // clamped rows -> unstored D columns
    const float* hrow = h + (size_t)arow * F_DIM + q * 8;

    floatx4 c0 = {0.f, 0.f, 0.f, 0.f};   // u half: D[o][node]
    floatx4 c1 = {0.f, 0.f, 0.f, 0.f};   // v half

    #pragma unroll
    for (int s = 0; s < 4; ++s) {
        float av[8];
        *(float4*)(av)     = *(const float4*)(hrow + s * 32);
        *(float4*)(av + 4) = *(const float4*)(hrow + s * 32 + 4);
        half8 ah, al;
        #pragma unroll
        for (int j = 0; j < 8; ++j) {
            _Float16 hi = (_Float16)av[j];
            ah[j] = hi;
            al[j] = (_Float16)(av[j] - (float)hi);
        }
        const int base0 = (s * 2 + 0) * 512 + lane * 8;
        const int base1 = (s * 2 + 1) * 512 + lane * 8;
        half8 wh0 = *(const half8*)(Bhi + base0);
        half8 wl0 = *(const half8*)(Blo + base0);
        half8 wh1 = *(const half8*)(Bhi + base1);
        half8 wl1 = *(const half8*)(Blo + base1);

        // D += A(W) * B(h): weight hi/lo split against h hi/lo split
        c0 = __builtin_amdgcn_mfma_f32_16x16x32_f16(wh0, ah, c0, 0, 0, 0);
        c0 = __builtin_amdgcn_mfma_f32_16x16x32_f16(wl0, ah, c0, 0, 0, 0);
        c0 = __builtin_amdgcn_mfma_f32_16x16x32_f16(wh0, al, c0, 0, 0, 0);
        c1 = __builtin_amdgcn_mfma_f32_16x16x32_f16(wh1, ah, c1, 0, 0, 0);
        c1 = __builtin_amdgcn_mfma_f32_16x16x32_f16(wl1, ah, c1, 0, 0, 0);
        c1 = __builtin_amdgcn_mfma_f32_16x16x32_f16(wh1, al, c1, 0, 0, 0);
    }

    const int node = row_base + n;      // D column this lane owns
    if (node < N) {
        const floatx4 bv = *(const floatx4*)(b + 4 * q);   // b[4q+reg]
        unsigned u0 = bf16_bits_rne(c0[0] + bv[0]) | (bf16_bits_rne(c0[1] + bv[1]) << 16);
        unsigned u1 = bf16_bits_rne(c0[2] + bv[2]) | (bf16_bits_rne(c0[3] + bv[3]) << 16);
        unsigned v0 = bf16_bits_rne(c1[0]) | (bf16_bits_rne(c1[1]) << 16);
        unsigned v1 = bf16_bits_rne(c1[2]) | (bf16_bits_rne(c1[3]) << 16);
        const size_t base = (size_t)node * 8 + 2 * q;
        Pu16[base]     = u0;
        Pu16[base + 1] = u1;
        Pv16[base]     = v0;
        Pv16[base + 1] = v1;
    }
}

// ---------------------------------------------------------------------------
// Kernel 2: out[e][o] = Pu[src[e]][o] + Pv[dst[e]][o]   (bias already in Pu)
// MLP version: 2 edges per LANE (was 1/2 edge). Each lane issues 2 coalesced
// 8B index loads (NT: read-once, keep L2 for tables), then 8 INDEPENDENT
// 16B table gathers in flight (was 2), then 128B contiguous NT stores.
// Same bytes, same math — 4x the outstanding scattered loads per thread.
__global__ __launch_bounds__(256) void gather2_kernel(
    const unsigned short* __restrict__ Pu, const unsigned short* __restrict__ Pv,
    const int* __restrict__ src, const int* __restrict__ dst,
    float* __restrict__ out, int E)
{
    const int tid = blockIdx.x * blockDim.x + threadIdx.x;
    const int e0 = tid * 2;
    if (e0 + 1 < E) {
        // Both index pairs first (independent, coalesced 8B loads).
        const intx2 s01 = __builtin_nontemporal_load((const intx2*)(src + e0));
        const intx2 d01 = __builtin_nontemporal_load((const intx2*)(dst + e0));

        // 8 independent scattered 16B loads — all in flight together.
        const us8* pus0 = (const us8*)(Pu + (size_t)s01[0] * 16);
        const us8* pvs0 = (const us8*)(Pv + (size_t)d01[0] * 16);
        const us8* pus1 = (const us8*)(Pu + (size_t)s01[1] * 16);
        const us8* pvs1 = (const us8*)(Pv + (size_t)d01[1] * 16);
        const us8 pu0a = pus0[0], pu0b = pus0[1];
        const us8 pv0a = pvs0[0], pv0b = pvs0[1];
        const us8 pu1a = pus1[0], pu1b = pus1[1];
        const us8 pv1a = pvs1[0], pv1b = pvs1[1];

        floatx4 r0, r1, r2, r3, r4, r5, r6, r7;
        #pragma unroll
        for (int j = 0; j < 4; ++j) {
            r0[j] = __uint_as_float((unsigned)pu0a[j] << 16)
                  + __uint_as_float((unsigned)pv0a[j] << 16);
            r1[j] = __uint_as_float((unsigned)pu0a[j + 4] << 16)
                  + __uint_as_float((unsigned)pv0a[j + 4] << 16);
            r2[j] = __uint_as_float((unsigned)pu0b[j] << 16)
                  + __uint_as_float((unsigned)pv0b[j] << 16);
            r3[j] = __uint_as_float((unsigned)pu0b[j + 4] << 16)
                  + __uint_as_float((unsigned)pv0b[j + 4] << 16);
            r4[j] = __uint_as_float((unsigned)pu1a[j] << 16)
                  + __uint_as_float((unsigned)pv1a[j] << 16);
            r5[j] = __uint_as_float((unsigned)pu1a[j + 4] << 16)
                  + __uint_as_float((unsigned)pv1a[j + 4] << 16);
            r6[j] = __uint_as_float((unsigned)pu1b[j] << 16)
                  + __uint_as_float((unsigned)pv1b[j] << 16);
            r7[j] = __uint_as_float((unsigned)pu1b[j + 4] << 16)
                  + __uint_as_float((unsigned)pv1b[j + 4] << 16);
        }
        floatx4* o = (floatx4*)out + (size_t)tid * 8;   // 128B contiguous
        __builtin_nontemporal_store(r0, o + 0);
        __builtin_nontemporal_store(r1, o + 1);
        __builtin_nontemporal_store(r2, o + 2);
        __builtin_nontemporal_store(r3, o + 3);
        __builtin_nontemporal_store(r4, o + 4);
        __builtin_nontemporal_store(r5, o + 5);
        __builtin_nontemporal_store(r6, o + 6);
        __builtin_nontemporal_store(r7, o + 7);
    } else if (e0 < E) {
        // Tail: single edge (E odd — not hit for E=640000, kept for safety).
        const int s = src[e0];
        const int d = dst[e0];
        const us8* pus = (const us8*)(Pu + (size_t)s * 16);
        const us8* pvs = (const us8*)(Pv + (size_t)d * 16);
        const us8 pua = pus[0], pub = pus[1];
        const us8 pva = pvs[0], pvb = pvs[1];
        floatx4 r0, r1;
        #pragma unroll
        for (int j = 0; j < 4; ++j) {
            r0[j] = __uint_as_float((unsigned)pua[j] << 16)
                  + __uint_as_float((unsigned)pva[j] << 16);
            r1[j] = __uint_as_float((unsigned)pua[j + 4] << 16)
                  + __uint_as_float((unsigned)pva[j + 4] << 16);
        }
        floatx4* o = (floatx4*)out + (size_t)e0 * 4;
        __builtin_nontemporal_store(r0, o);
        __builtin_nontemporal_store(r1, o + 1);
        #pragma unroll
        for (int j = 0; j < 4; ++j) {
            r0[j] = __uint_as_float((unsigned)pub[j] << 16)
                  + __uint_as_float((unsigned)pvb[j] << 16);
            r1[j] = __uint_as_float((unsigned)pub[j + 4] << 16)
                  + __uint_as_float((unsigned)pvb[j + 4] << 16);
        }
        __builtin_nontemporal_store(r0, o + 2);
        __builtin_nontemporal_store(r1, o + 3);
    }
}

// Fallback (only if workspace too small): direct per-(edge,out) dot, fp32.
__global__ __launch_bounds__(256) void direct_kernel(
    const float* __restrict__ h, const int* __restrict__ src,
    const int* __restrict__ dst, const float* __restrict__ W,
    const float* __restrict__ b, float* __restrict__ out, int E)
{
    const int tid = blockIdx.x * blockDim.x + threadIdx.x;
    if (tid >= E * OUT_DIM) return;
    const int e = tid >> 4;
    const int o = tid & 15;
    const float* hu = h + (size_t)src[e] * F_DIM;
    const float* hv = h + (size_t)dst[e] * F_DIM;
    const float* wu = W + (size_t)o * 256;
    const float* wv = wu + 128;
    float acc = b[o];
    for (int k = 0; k < 128; ++k) acc = fmaf(hu[k], wu[k], acc);
    for (int k = 0; k < 128; ++k) acc = fmaf(hv[k], wv[k], acc);
    out[tid] = acc;
}

extern "C" void kernel_launch(void* const* d_in, const int* in_sizes, int n_in,
                              void* d_out, int out_size, void* d_ws, size_t ws_size,
                              hipStream_t stream) {
    const float* h   = (const float*)d_in[0];
    const int*   src = (const int*)d_in[1];
    const int*   dst = (const int*)d_in[2];
    const float* W   = (const float*)d_in[3];
    const float* b   = (const float*)d_in[4];
    float* out = (float*)d_out;

    const int N = in_sizes[0] / F_DIM;     // 100000
    const int E = in_sizes[1];             // 640000

    const size_t p16_bytes = (size_t)N * 8 * sizeof(unsigned);    // 3.2 MB
    const size_t p16_al    = (p16_bytes + 255) & ~(size_t)255;
    const size_t bf_bytes  = 4096 * sizeof(_Float16);             // 8 KB each

    if (ws_size >= 2 * p16_al + 2 * bf_bytes) {
        unsigned int* Pu16 = (unsigned int*)d_ws;
        unsigned int* Pv16 = (unsigned int*)((char*)d_ws + p16_al);
        _Float16*     Bhi  = (_Float16*)((char*)d_ws + 2 * p16_al);
        _Float16*     Blo  = Bhi + 4096;

        wprep_kernel<<<16, 256, 0, stream>>>(W, Bhi, Blo);

        const int blocks1 = (N + 63) / 64;
        proj_mfma_kernel<<<blocks1, 256, 0, stream>>>(h, Bhi, Blo, b, Pu16, Pv16, N);

        const int threads2 = (E + 1) / 2;               // 2 edges per lane
        const int blocks2  = (threads2 + 255) / 256;    // 1250 blocks
        gather2_kernel<<<blocks2, 256, 0, stream>>>(
            (const unsigned short*)Pu16, (const unsigned short*)Pv16,
            src, dst, out, E);
    } else {
        const int total  = E * OUT_DIM;
        const int blocks = (total + 255) / 256;
        direct_kernel<<<blocks, 256, 0, stream>>>(h, src, dst, W, b, out, E);
    }
}

// Round 4
// 126.338 us; speedup vs baseline: 1.8414x; 1.2247x over previous
//
#include <hip/hip_runtime.h>
#include <hip/hip_bf16.h>

// Problem constants (from reference): N=100000, F=128, E=640000, OUT=16
#define F_DIM 128
#define OUT_DIM 16

typedef _Float16 half8 __attribute__((ext_vector_type(8)));
typedef float floatx4 __attribute__((ext_vector_type(4)));
typedef unsigned short us8 __attribute__((ext_vector_type(8)));

// ---------------------------------------------------------------------------
// Kernel 0: build fp16 hi/lo weight fragments (k = quad*8+j, lane&15 = o).
// 8 KB per term, read L1-hot as wave-uniform broadcasts in proj.
__global__ __launch_bounds__(256) void wprep_kernel(
    const float* __restrict__ W, _Float16* __restrict__ Bhi,
    _Float16* __restrict__ Blo)
{
    int tid = blockIdx.x * 256 + threadIdx.x;     // 0..4095
    if (tid >= 4096) return;
    int j    = tid & 7;
    int lane = (tid >> 3) & 63;
    int t    = (tid >> 9) & 1;
    int s    = (tid >> 10) & 3;
    int n = lane & 15;
    int q = lane >> 4;
    int k = s * 32 + q * 8 + j;
    float w = W[n * 256 + t * 128 + k];
    _Float16 hi = (_Float16)w;
    _Float16 lo = (_Float16)(w - (float)hi);
    Bhi[tid] = hi;
    Blo[tid] = lo;
}

__device__ __forceinline__ unsigned bf16_bits_rne(float f) {
    unsigned u = __builtin_bit_cast(unsigned, f);
    unsigned rounding = 0x7FFFu + ((u >> 16) & 1u);
    return (u + rounding) >> 16;          // RNE; NaN not possible here
}

// ---------------------------------------------------------------------------
// Kernel 1: Pu16[node][o] = bf16(h[node].Wu + b) ; Pv16 likewise (no bias).
// TRANSPOSED MFMA: D[m=o][n=node] = sum_k W'[o][k] * h[node][k]
// Byte-identical to the verified 125.9 µs baseline.
__global__ __launch_bounds__(256) void proj_mfma_kernel(
    const float* __restrict__ h, const _Float16* __restrict__ Bhi,
    const _Float16* __restrict__ Blo, const float* __restrict__ b,
    unsigned int* __restrict__ Pu16, unsigned int* __restrict__ Pv16, int N)
{
    const int lane = threadIdx.x & 63;
    const int wave = threadIdx.x >> 6;
    const int n = lane & 15;            // node within tile
    const int q = lane >> 4;            // quad: o-group and k-group selector
    const int row_base = blockIdx.x * 64 + wave * 16;
    if (row_base >= N) return;          // whole wave exits; no barriers below

    int arow = row_base + n;            // h row this lane feeds (B operand)
    if (arow >= N) arow = N - 1;        // clamped rows -> unstored D columns
    const float* hrow = h + (size_t)arow * F_DIM + q * 8;

    floatx4 c0 = {0.f, 0.f, 0.f, 0.f};   // u half: D[o][node]
    floatx4 c1 = {0.f, 0.f, 0.f, 0.f};   // v half

    #pragma unroll
    for (int s = 0; s < 4; ++s) {
        float av[8];
        *(float4*)(av)     = *(const float4*)(hrow + s * 32);
        *(float4*)(av + 4) = *(const float4*)(hrow + s * 32 + 4);
        half8 ah, al;
        #pragma unroll
        for (int j = 0; j < 8; ++j) {
            _Float16 hi = (_Float16)av[j];
            ah[j] = hi;
            al[j] = (_Float16)(av[j] - (float)hi);
        }
        const int base0 = (s * 2 + 0) * 512 + lane * 8;
        const int base1 = (s * 2 + 1) * 512 + lane * 8;
        half8 wh0 = *(const half8*)(Bhi + base0);
        half8 wl0 = *(const half8*)(Blo + base0);
        half8 wh1 = *(const half8*)(Bhi + base1);
        half8 wl1 = *(const half8*)(Blo + base1);

        // D += A(W) * B(h): weight hi/lo split against h hi/lo split
        c0 = __builtin_amdgcn_mfma_f32_16x16x32_f16(wh0, ah, c0, 0, 0, 0);
        c0 = __builtin_amdgcn_mfma_f32_16x16x32_f16(wl0, ah, c0, 0, 0, 0);
        c0 = __builtin_amdgcn_mfma_f32_16x16x32_f16(wh0, al, c0, 0, 0, 0);
        c1 = __builtin_amdgcn_mfma_f32_16x16x32_f16(wh1, ah, c1, 0, 0, 0);
        c1 = __builtin_amdgcn_mfma_f32_16x16x32_f16(wl1, ah, c1, 0, 0, 0);
        c1 = __builtin_amdgcn_mfma_f32_16x16x32_f16(wh1, al, c1, 0, 0, 0);
    }

    const int node = row_base + n;      // D column this lane owns
    if (node < N) {
        const floatx4 bv = *(const floatx4*)(b + 4 * q);   // b[4q+reg]
        unsigned u0 = bf16_bits_rne(c0[0] + bv[0]) | (bf16_bits_rne(c0[1] + bv[1]) << 16);
        unsigned u1 = bf16_bits_rne(c0[2] + bv[2]) | (bf16_bits_rne(c0[3] + bv[3]) << 16);
        unsigned v0 = bf16_bits_rne(c1[0]) | (bf16_bits_rne(c1[1]) << 16);
        unsigned v1 = bf16_bits_rne(c1[2]) | (bf16_bits_rne(c1[3]) << 16);
        const size_t base = (size_t)node * 8 + 2 * q;
        Pu16[base]     = u0;
        Pu16[base + 1] = u1;
        Pv16[base]     = v0;
        Pv16[base + 1] = v1;
    }
}

// ---------------------------------------------------------------------------
// Kernel 2: out[e][o] = Pu[src[e]][o] + Pv[dst[e]][o]   (bias already in Pu)
// MLP version with R0's PROVEN store geometry. Item space = 2E half-edges;
// item -> (e = item>>1, q = item&1), 32B stored at out + 32*item, adjacent
// items adjacent (per-instruction stride 32B across lanes — the pattern that
// measured no write amplification). Each thread handles 4 items spaced
// T = ceil(2E/4) apart: 4 independent {idx loads -> 2 gathers} chains,
// 8 scattered 16B table loads in flight, 4 R0-coalesced store regions.
__global__ __launch_bounds__(256) void gather4_kernel(
    const unsigned short* __restrict__ Pu, const unsigned short* __restrict__ Pv,
    const int* __restrict__ src, const int* __restrict__ dst,
    float* __restrict__ out, int E)
{
    const int total = 2 * E;                    // item count
    const int T = (total + 3) >> 2;             // items per quarter = threads
    const int t = blockIdx.x * blockDim.x + threadIdx.x;
    if (t >= T) return;

    int it[4];
    #pragma unroll
    for (int k = 0; k < 4; ++k) it[k] = t + k * T;

    // Phase A: all index loads issued together (independent, coalesced;
    // adjacent lanes share e = item>>1 -> broadcast within the pair).
    int si[4], di[4];
    #pragma unroll
    for (int k = 0; k < 4; ++k) {
        const int e = (it[k] < total) ? (it[k] >> 1) : 0;
        si[k] = src[e];
        di[k] = dst[e];
    }

    // Phase B: all 8 scattered 16B table gathers in flight together.
    us8 pu[4], pv[4];
    #pragma unroll
    for (int k = 0; k < 4; ++k) {
        const int q = it[k] & 1;
        pu[k] = *(const us8*)(Pu + (size_t)si[k] * 16 + q * 8);
        pv[k] = *(const us8*)(Pv + (size_t)di[k] * 16 + q * 8);
    }

    // Phase C: convert + store (R0 geometry per region).
    #pragma unroll
    for (int k = 0; k < 4; ++k) {
        if (it[k] >= total) continue;
        floatx4 r0, r1;
        #pragma unroll
        for (int j = 0; j < 4; ++j) {
            r0[j] = __uint_as_float((unsigned)pu[k][j] << 16)
                  + __uint_as_float((unsigned)pv[k][j] << 16);
            r1[j] = __uint_as_float((unsigned)pu[k][j + 4] << 16)
                  + __uint_as_float((unsigned)pv[k][j + 4] << 16);
        }
        floatx4* o = (floatx4*)out + (size_t)it[k] * 2;
        __builtin_nontemporal_store(r0, o);
        __builtin_nontemporal_store(r1, o + 1);
    }
}

// Fallback (only if workspace too small): direct per-(edge,out) dot, fp32.
__global__ __launch_bounds__(256) void direct_kernel(
    const float* __restrict__ h, const int* __restrict__ src,
    const int* __restrict__ dst, const float* __restrict__ W,
    const float* __restrict__ b, float* __restrict__ out, int E)
{
    const int tid = blockIdx.x * blockDim.x + threadIdx.x;
    if (tid >= E * OUT_DIM) return;
    const int e = tid >> 4;
    const int o = tid & 15;
    const float* hu = h + (size_t)src[e] * F_DIM;
    const float* hv = h + (size_t)dst[e] * F_DIM;
    const float* wu = W + (size_t)o * 256;
    const float* wv = wu + 128;
    float acc = b[o];
    for (int k = 0; k < 128; ++k) acc = fmaf(hu[k], wu[k], acc);
    for (int k = 0; k < 128; ++k) acc = fmaf(hv[k], wv[k], acc);
    out[tid] = acc;
}

extern "C" void kernel_launch(void* const* d_in, const int* in_sizes, int n_in,
                              void* d_out, int out_size, void* d_ws, size_t ws_size,
                              hipStream_t stream) {
    const float* h   = (const float*)d_in[0];
    const int*   src = (const int*)d_in[1];
    const int*   dst = (const int*)d_in[2];
    const float* W   = (const float*)d_in[3];
    const float* b   = (const float*)d_in[4];
    float* out = (float*)d_out;

    const int N = in_sizes[0] / F_DIM;     // 100000
    const int E = in_sizes[1];             // 640000

    const size_t p16_bytes = (size_t)N * 8 * sizeof(unsigned);    // 3.2 MB
    const size_t p16_al    = (p16_bytes + 255) & ~(size_t)255;
    const size_t bf_bytes  = 4096 * sizeof(_Float16);             // 8 KB each

    if (ws_size >= 2 * p16_al + 2 * bf_bytes) {
        unsigned int* Pu16 = (unsigned int*)d_ws;
        unsigned int* Pv16 = (unsigned int*)((char*)d_ws + p16_al);
        _Float16*     Bhi  = (_Float16*)((char*)d_ws + 2 * p16_al);
        _Float16*     Blo  = Bhi + 4096;

        wprep_kernel<<<16, 256, 0, stream>>>(W, Bhi, Blo);

        const int blocks1 = (N + 63) / 64;
        proj_mfma_kernel<<<blocks1, 256, 0, stream>>>(h, Bhi, Blo, b, Pu16, Pv16, N);

        const int threads2 = (2 * E + 3) / 4;           // 4 items per thread
        const int blocks2  = (threads2 + 255) / 256;    // 1250 blocks
        gather4_kernel<<<blocks2, 256, 0, stream>>>(
            (const unsigned short*)Pu16, (const unsigned short*)Pv16,
            src, dst, out, E);
    } else {
        const int total  = E * OUT_DIM;
        const int blocks = (total + 255) / 256;
        direct_kernel<<<blocks, 256, 0, stream>>>(h, src, dst, W, b, out, E);
    }
}

// Round 5
// 122.225 us; speedup vs baseline: 1.9033x; 1.0337x over previous
//
#include <hip/hip_runtime.h>
#include <hip/hip_bf16.h>

// Problem constants (from reference): N=100000, F=128, E=640000, OUT=16
#define F_DIM 128
#define OUT_DIM 16

typedef _Float16 half8 __attribute__((ext_vector_type(8)));
typedef float floatx4 __attribute__((ext_vector_type(4)));
typedef unsigned short us8 __attribute__((ext_vector_type(8)));

__device__ __forceinline__ unsigned bf16_bits_rne(float f) {
    unsigned u = __builtin_bit_cast(unsigned, f);
    unsigned rounding = 0x7FFFu + ((u >> 16) & 1u);
    return (u + rounding) >> 16;          // RNE; NaN not possible here
}

// ---------------------------------------------------------------------------
// Kernel 1 (FUSED wprep+proj):
//   Phase 0: per-block LDS build of fp16 hi/lo weight fragments from W
//            (identical math to the old wprep_kernel; W is 16KB, L2-hot;
//            R1 measured this phase with SQ_LDS_BANK_CONFLICT = 0).
//   Phase 1: Pu16[node][o] = bf16(h[node].Wu + b); Pv16 likewise (no bias).
//            TRANSPOSED MFMA: D[m=o][n=node] = sum_k W'[o][k] * h[node][k].
//            NEW: all 8 h-loads hoisted into registers BEFORE any compute —
//            8 loads in flight per wave (was ~2 at VGPR=56) to cover HBM
//            latency with MLP instead of (insufficient) TLP alone.
__global__ __launch_bounds__(256) void proj_fused_kernel(
    const float* __restrict__ h, const float* __restrict__ W,
    const float* __restrict__ b,
    unsigned int* __restrict__ Pu16, unsigned int* __restrict__ Pv16, int N)
{
    __shared__ __align__(16) _Float16 sBhi[4096];
    __shared__ __align__(16) _Float16 sBlo[4096];
    for (int i = threadIdx.x; i < 4096; i += 256) {
        const int j  = i & 7;
        const int ln = (i >> 3) & 63;
        const int t  = (i >> 9) & 1;
        const int s  = (i >> 10) & 3;
        const int n2 = ln & 15;
        const int q2 = ln >> 4;
        const int k  = s * 32 + q2 * 8 + j;
        const float w = W[n2 * 256 + t * 128 + k];
        const _Float16 hi = (_Float16)w;
        sBhi[i] = hi;
        sBlo[i] = (_Float16)(w - (float)hi);
    }
    __syncthreads();

    const int lane = threadIdx.x & 63;
    const int wave = threadIdx.x >> 6;
    const int n = lane & 15;            // node within tile
    const int q = lane >> 4;            // quad: o-group and k-group selector
    const int row_base = blockIdx.x * 64 + wave * 16;
    if (row_base >= N) return;          // after the one barrier; no more below

    int arow = row_base + n;            // h row this lane feeds (B operand)
    if (arow >= N) arow = N - 1;        // clamped rows -> unstored D columns
    const float* hrow = h + (size_t)arow * F_DIM + q * 8;

    // All h loads issued up-front: 8 independent 16B loads in flight.
    floatx4 av[8];
    #pragma unroll
    for (int s = 0; s < 4; ++s) {
        av[2 * s]     = *(const floatx4*)(hrow + s * 32);
        av[2 * s + 1] = *(const floatx4*)(hrow + s * 32 + 4);
    }

    floatx4 c0 = {0.f, 0.f, 0.f, 0.f};   // u half: D[o][node]
    floatx4 c1 = {0.f, 0.f, 0.f, 0.f};   // v half

    #pragma unroll
    for (int s = 0; s < 4; ++s) {
        half8 ah, al;
        #pragma unroll
        for (int j = 0; j < 8; ++j) {     // static indexing after unroll
            const float x = (j < 4) ? av[2 * s][j] : av[2 * s + 1][j - 4];
            const _Float16 hi = (_Float16)x;
            ah[j] = hi;
            al[j] = (_Float16)(x - (float)hi);
        }
        const int base0 = (s * 2 + 0) * 512 + lane * 8;
        const int base1 = (s * 2 + 1) * 512 + lane * 8;
        const half8 wh0 = *(const half8*)(sBhi + base0);
        const half8 wl0 = *(const half8*)(sBlo + base0);
        const half8 wh1 = *(const half8*)(sBhi + base1);
        const half8 wl1 = *(const half8*)(sBlo + base1);

        // D += A(W) * B(h): weight hi/lo split against h hi/lo split
        c0 = __builtin_amdgcn_mfma_f32_16x16x32_f16(wh0, ah, c0, 0, 0, 0);
        c0 = __builtin_amdgcn_mfma_f32_16x16x32_f16(wl0, ah, c0, 0, 0, 0);
        c0 = __builtin_amdgcn_mfma_f32_16x16x32_f16(wh0, al, c0, 0, 0, 0);
        c1 = __builtin_amdgcn_mfma_f32_16x16x32_f16(wh1, ah, c1, 0, 0, 0);
        c1 = __builtin_amdgcn_mfma_f32_16x16x32_f16(wl1, ah, c1, 0, 0, 0);
        c1 = __builtin_amdgcn_mfma_f32_16x16x32_f16(wh1, al, c1, 0, 0, 0);
    }

    const int node = row_base + n;      // D column this lane owns
    if (node < N) {
        const floatx4 bv = *(const floatx4*)(b + 4 * q);   // b[4q+reg]
        unsigned u0 = bf16_bits_rne(c0[0] + bv[0]) | (bf16_bits_rne(c0[1] + bv[1]) << 16);
        unsigned u1 = bf16_bits_rne(c0[2] + bv[2]) | (bf16_bits_rne(c0[3] + bv[3]) << 16);
        unsigned v0 = bf16_bits_rne(c1[0]) | (bf16_bits_rne(c1[1]) << 16);
        unsigned v1 = bf16_bits_rne(c1[2]) | (bf16_bits_rne(c1[3]) << 16);
        const size_t base = (size_t)node * 8 + 2 * q;
        Pu16[base]     = u0;
        Pu16[base + 1] = u1;
        Pv16[base]     = v0;
        Pv16[base + 1] = v1;
    }
}

// ---------------------------------------------------------------------------
// Kernel 2: out[e][o] = Pu[src[e]][o] + Pv[dst[e]][o]   (bias already in Pu)
// Unchanged from Round 4 (proven: restored R0 store geometry, ~23 µs).
__global__ __launch_bounds__(256) void gather4_kernel(
    const unsigned short* __restrict__ Pu, const unsigned short* __restrict__ Pv,
    const int* __restrict__ src, const int* __restrict__ dst,
    float* __restrict__ out, int E)
{
    const int total = 2 * E;                    // item count
    const int T = (total + 3) >> 2;             // items per quarter = threads
    const int t = blockIdx.x * blockDim.x + threadIdx.x;
    if (t >= T) return;

    int it[4];
    #pragma unroll
    for (int k = 0; k < 4; ++k) it[k] = t + k * T;

    // Phase A: all index loads issued together (independent, coalesced;
    // adjacent lanes share e = item>>1 -> broadcast within the pair).
    int si[4], di[4];
    #pragma unroll
    for (int k = 0; k < 4; ++k) {
        const int e = (it[k] < total) ? (it[k] >> 1) : 0;
        si[k] = src[e];
        di[k] = dst[e];
    }

    // Phase B: all 8 scattered 16B table gathers in flight together.
    us8 pu[4], pv[4];
    #pragma unroll
    for (int k = 0; k < 4; ++k) {
        const int q = it[k] & 1;
        pu[k] = *(const us8*)(Pu + (size_t)si[k] * 16 + q * 8);
        pv[k] = *(const us8*)(Pv + (size_t)di[k] * 16 + q * 8);
    }

    // Phase C: convert + store (R0 geometry per region).
    #pragma unroll
    for (int k = 0; k < 4; ++k) {
        if (it[k] >= total) continue;
        floatx4 r0, r1;
        #pragma unroll
        for (int j = 0; j < 4; ++j) {
            r0[j] = __uint_as_float((unsigned)pu[k][j] << 16)
                  + __uint_as_float((unsigned)pv[k][j] << 16);
            r1[j] = __uint_as_float((unsigned)pu[k][j + 4] << 16)
                  + __uint_as_float((unsigned)pv[k][j + 4] << 16);
        }
        floatx4* o = (floatx4*)out + (size_t)it[k] * 2;
        __builtin_nontemporal_store(r0, o);
        __builtin_nontemporal_store(r1, o + 1);
    }
}

// Fallback (only if workspace too small): direct per-(edge,out) dot, fp32.
__global__ __launch_bounds__(256) void direct_kernel(
    const float* __restrict__ h, const int* __restrict__ src,
    const int* __restrict__ dst, const float* __restrict__ W,
    const float* __restrict__ b, float* __restrict__ out, int E)
{
    const int tid = blockIdx.x * blockDim.x + threadIdx.x;
    if (tid >= E * OUT_DIM) return;
    const int e = tid >> 4;
    const int o = tid & 15;
    const float* hu = h + (size_t)src[e] * F_DIM;
    const float* hv = h + (size_t)dst[e] * F_DIM;
    const float* wu = W + (size_t)o * 256;
    const float* wv = wu + 128;
    float acc = b[o];
    for (int k = 0; k < 128; ++k) acc = fmaf(hu[k], wu[k], acc);
    for (int k = 0; k < 128; ++k) acc = fmaf(hv[k], wv[k], acc);
    out[tid] = acc;
}

extern "C" void kernel_launch(void* const* d_in, const int* in_sizes, int n_in,
                              void* d_out, int out_size, void* d_ws, size_t ws_size,
                              hipStream_t stream) {
    const float* h   = (const float*)d_in[0];
    const int*   src = (const int*)d_in[1];
    const int*   dst = (const int*)d_in[2];
    const float* W   = (const float*)d_in[3];
    const float* b   = (const float*)d_in[4];
    float* out = (float*)d_out;

    const int N = in_sizes[0] / F_DIM;     // 100000
    const int E = in_sizes[1];             // 640000

    const size_t p16_bytes = (size_t)N * 8 * sizeof(unsigned);    // 3.2 MB
    const size_t p16_al    = (p16_bytes + 255) & ~(size_t)255;

    if (ws_size >= 2 * p16_al) {
        unsigned int* Pu16 = (unsigned int*)d_ws;
        unsigned int* Pv16 = (unsigned int*)((char*)d_ws + p16_al);

        const int blocks1 = (N + 63) / 64;
        proj_fused_kernel<<<blocks1, 256, 0, stream>>>(h, W, b, Pu16, Pv16, N);

        const int threads2 = (2 * E + 3) / 4;           // 4 items per thread
        const int blocks2  = (threads2 + 255) / 256;    // 1250 blocks
        gather4_kernel<<<blocks2, 256, 0, stream>>>(
            (const unsigned short*)Pu16, (const unsigned short*)Pv16,
            src, dst, out, E);
    } else {
        const int total  = E * OUT_DIM;
        const int blocks = (total + 255) / 256;
        direct_kernel<<<blocks, 256, 0, stream>>>(h, src, dst, W, b, out, E);
    }
}